// Round 3
// baseline (180.849 us; speedup 1.0000x reference)
//
#include <hip/hip_runtime.h>
#include <hip/hip_bf16.h>
#include <cstddef>

#define SNL_N 50000
#define SNL_K 32
#define SNL_D 128
#define SNL_EPS 1e-12f
#define SNL_NBLOCKS 6250   // x2 groups each, 4 rows/group -> 50000 exact

// One wave per row i. lane = asub*8 + dc. All 16 yj float4 gathers issued
// back-to-back into registers (MLP=16 lines in flight per wave) before any
// fma -- round 2 showed we were latency x concurrency bound (VGPR=60 forced
// the compiler to serialize gathers ~2-4 deep).
__global__ __launch_bounds__(256) void snl_main(const float* __restrict__ emb,
                                                const float* __restrict__ psim,
                                                const int* __restrict__ aidx,
                                                float* __restrict__ out,
                                                float* __restrict__ part) {
    const int tid  = threadIdx.x;
    const int wid  = tid >> 6;       // wave in block
    const int lane = tid & 63;
    const int dc   = lane & 7;       // 16B chunk (0..7) -> one 128B line per 8 lanes
    const int asub = lane >> 3;      // anchor-in-group-of-8 (0..7)

    const float4* emb4 = reinterpret_cast<const float4*>(emb);

    float loss_acc = 0.0f;

#pragma unroll 1
    for (int rep = 0; rep < 2; ++rep) {
        const int i = (blockIdx.x * 2 + rep) * 4 + wid;

        // anchor indices for all 4 octets first (yj addresses depend on them)
        int a[4];
#pragma unroll
        for (int g = 0; g < 4; ++g)
            a[g] = aidx[(size_t)i * SNL_K + g * 8 + asub];

        // yi: 4 broadcast float4 chunks (independent of a, overlaps idx loads)
        float4 yir[4];
#pragma unroll
        for (int it = 0; it < 4; ++it)
            yir[it] = emb4[(size_t)i * 32 + dc + it * 8];

        // all 16 gather loads issued before any use
        float4 yj[16];
#pragma unroll
        for (int g = 0; g < 4; ++g) {
            const float4* jr = emb4 + (size_t)a[g] * 32;
#pragma unroll
            for (int it = 0; it < 4; ++it)
                yj[g * 4 + it] = jr[dc + it * 8];
        }

        float d2g[4];
#pragma unroll
        for (int g = 0; g < 4; ++g) {
            float acc = 0.0f;
#pragma unroll
            for (int it = 0; it < 4; ++it) {
                const float4 v = yj[g * 4 + it];
                float dx = yir[it].x - v.x;
                float dy = yir[it].y - v.y;
                float dz = yir[it].z - v.z;
                float dw = yir[it].w - v.w;
                acc = fmaf(dx, dx, acc);
                acc = fmaf(dy, dy, acc);
                acc = fmaf(dz, dz, acc);
                acc = fmaf(dw, dw, acc);
            }
            acc += __shfl_xor(acc, 1, 64);
            acc += __shfl_xor(acc, 2, 64);
            acc += __shfl_xor(acc, 4, 64);
            d2g[g] = acc;
        }

        // transpose: lane k (and mirror k+32) gets d2 of anchor k
        const int src = (lane & 7) * 8;
        float t0 = __shfl(d2g[0], src, 64);
        float t1 = __shfl(d2g[1], src, 64);
        float t2 = __shfl(d2g[2], src, 64);
        float t3 = __shfl(d2g[3], src, 64);
        const int gsel = (lane >> 3) & 3;
        float d2 = (gsel == 0) ? t0 : (gsel == 1) ? t1 : (gsel == 2) ? t2 : t3;

        // 32-lane softmax (xor offsets 1..16 stay within each half)
        const float s = -d2;
        float m = s;
#pragma unroll
        for (int off = 1; off < 32; off <<= 1)
            m = fmaxf(m, __shfl_xor(m, off, 64));
        const float e = expf(s - m);
        float ss = e;
#pragma unroll
        for (int off = 1; off < 32; off <<= 1)
            ss += __shfl_xor(ss, off, 64);
        const float logq = (s - m) - logf(ss);
        const float q = e / ss;

        if (lane < SNL_K) {
            out[1 + (size_t)i * SNL_K + lane] = q;      // coalesced 128B store
            const float pv = psim[(size_t)i * SNL_K + lane];
            loss_acc += pv * (logf(pv + SNL_EPS) - logq);
        }
    }

    // block reduction of loss partial
#pragma unroll
    for (int off = 1; off < 64; off <<= 1)
        loss_acc += __shfl_xor(loss_acc, off, 64);

    __shared__ float bred[4];
    if (lane == 0) bred[wid] = loss_acc;
    __syncthreads();
    if (tid == 0) part[blockIdx.x] = bred[0] + bred[1] + bred[2] + bred[3];
}

__global__ __launch_bounds__(256) void snl_loss_reduce(const float* __restrict__ part,
                                                       int npart,
                                                       float* __restrict__ out) {
    double acc = 0.0;
    for (int i = threadIdx.x; i < npart; i += 256) acc += (double)part[i];
#pragma unroll
    for (int off = 1; off < 64; off <<= 1)
        acc += __shfl_xor(acc, off, 64);
    __shared__ double sred[4];
    if ((threadIdx.x & 63) == 0) sred[threadIdx.x >> 6] = acc;
    __syncthreads();
    if (threadIdx.x == 0)
        out[0] = (float)((sred[0] + sred[1] + sred[2] + sred[3]) / (double)SNL_N);
}

extern "C" void kernel_launch(void* const* d_in, const int* in_sizes, int n_in,
                              void* d_out, int out_size, void* d_ws, size_t ws_size,
                              hipStream_t stream) {
    const float* emb  = (const float*)d_in[0];
    const float* psim = (const float*)d_in[1];
    const int*   aidx = (const int*)d_in[2];
    float* out  = (float*)d_out;
    float* part = (float*)d_ws;   // SNL_NBLOCKS floats = 25 KB

    snl_main<<<SNL_NBLOCKS, 256, 0, stream>>>(emb, psim, aidx, out, part);
    snl_loss_reduce<<<1, 256, 0, stream>>>(part, SNL_NBLOCKS, out);
}